// Round 6
// baseline (818.694 us; speedup 1.0000x reference)
//
#include <hip/hip_runtime.h>
#include <stdint.h>

// mGRU fused: B=8, S=2048, IN=1024, HID=1024;  M=16384, K=2048, N=1024
// Round 6: (1) padded row strides (A/W: 2056 elems = 4112B; H2: 1032) to break
// 4KB L2-channel aliasing; (2) ring unrolled x3 (static LDS buffer indices);
// (3) abl_kloop instrument (K-loop x2, no epilogue) launched last.

#define M_ROWS 16384
#define K_DIM  2048
#define N_DIM  1024
#define LDA    2056   // padded stride for Abf / W1b / W2b (elements)
#define LDH2   1032   // padded stride for H2 (elements)

typedef float  f32x4  __attribute__((ext_vector_type(4)));
typedef __bf16 bf16x8 __attribute__((ext_vector_type(8)));
typedef unsigned short u16x8 __attribute__((ext_vector_type(8)));

typedef __attribute__((address_space(3))) void as3_void;
typedef __attribute__((address_space(1))) void as1_void;

__device__ __forceinline__ void gload_lds16(const unsigned short* g, void* lds) {
    __builtin_amdgcn_global_load_lds((const as1_void*)g, (as3_void*)lds, 16, 0, 0);
}

__device__ __forceinline__ unsigned short f2bf(float f) {
    union { float f; unsigned u; } v; v.f = f;
    unsigned r = 0x7FFFu + ((v.u >> 16) & 1u);
    return (unsigned short)((v.u + r) >> 16);
}

// ---------------- pack kernels (write PADDED layouts) ----------------

__global__ void pack_A(const float* __restrict__ x, const float* __restrict__ h,
                       unsigned short* __restrict__ Abf) {
    int t = blockIdx.x * 256 + threadIdx.x;      // 4,194,304 threads
    int row = t >> 8;
    int col = (t & 255) * 8;                     // 0..2040
    const float* src = (col < 1024) ? (x + (size_t)row * 1024 + col)
                                    : (h + (size_t)row * 1024 + (col - 1024));
    f32x4 v0 = ((const f32x4*)src)[0];
    f32x4 v1 = ((const f32x4*)src)[1];
    u16x8 o;
    o[0] = f2bf(v0[0]); o[1] = f2bf(v0[1]); o[2] = f2bf(v0[2]); o[3] = f2bf(v0[3]);
    o[4] = f2bf(v1[0]); o[5] = f2bf(v1[1]); o[6] = f2bf(v1[2]); o[7] = f2bf(v1[3]);
    *(u16x8*)(Abf + (size_t)row * LDA + col) = o;
}

__global__ void pack_W(const float* __restrict__ W1, const float* __restrict__ W2,
                       unsigned short* __restrict__ W1b, unsigned short* __restrict__ W2b) {
    int t = blockIdx.x * 256 + threadIdx.x;      // 524,288 threads
    int which = t >> 18;
    int r = (t >> 8) & 1023;
    int col = (t & 255) * 8;
    const float* src = (which ? W2 : W1) + (size_t)r * 2048 + col;
    unsigned short* dst = (which ? W2b : W1b) + (size_t)r * LDA + col;
    f32x4 v0 = ((const f32x4*)src)[0];
    f32x4 v1 = ((const f32x4*)src)[1];
    u16x8 o;
    o[0] = f2bf(v0[0]); o[1] = f2bf(v0[1]); o[2] = f2bf(v0[2]); o[3] = f2bf(v0[3]);
    o[4] = f2bf(v1[0]); o[5] = f2bf(v1[1]); o[6] = f2bf(v1[2]); o[7] = f2bf(v1[3]);
    *(u16x8*)dst = o;
}

// ---------------- GEMM: 128x128 tile, BK=32, 4 waves, 3-deep ring, unroll x3 ----------------

#define NT (K_DIM / 32)   // 64 K-steps

#define COMPUTE_C(c)                                                       \
  {                                                                        \
    bf16x8 af[4], bfr[4];                                                  \
    _Pragma("unroll") for (int i = 0; i < 4; i++) {                        \
      af[i]  = *(const bf16x8*)&As[c][(wr*64 + i*16 + fr)*32 + fq*8];      \
      bfr[i] = *(const bf16x8*)&Bs[c][(wc*64 + i*16 + fr)*32 + fq*8];      \
    }                                                                      \
    __builtin_amdgcn_s_setprio(1);                                         \
    _Pragma("unroll") for (int mi = 0; mi < 4; mi++)                       \
      _Pragma("unroll") for (int ni = 0; ni < 4; ni++)                     \
        acc[mi][ni] = __builtin_amdgcn_mfma_f32_16x16x32_bf16(             \
            af[mi], bfr[ni], acc[mi][ni], 0, 0, 0);                        \
    __builtin_amdgcn_s_setprio(0);                                         \
  }

__global__ __launch_bounds__(256) void gemm1(
        const unsigned short* __restrict__ Abf,  // [M][LDA] bf16
        const unsigned short* __restrict__ Wb,   // [1024][LDA] bf16
        const float* __restrict__ bias,
        const float* __restrict__ h,             // [M][1024] fp32
        float* Fout,                             // [M][1024] fp32 (d_out scratch)
        unsigned short* __restrict__ H2)         // [M][LDH2] bf16
{
    __shared__ unsigned short As[3][4096];
    __shared__ unsigned short Bs[3][4096];

    int bid = blockIdx.x;
    int wg  = (bid & 7) * 128 + (bid >> 3);
    int tn = wg & 7, tm = wg >> 3;
    int m0 = tm * 128, n0 = tn * 128;

    int t = threadIdx.x, wave = t >> 6, lane = t & 63;
    int wr = wave >> 1, wc = wave & 1;
    int fr = lane & 15, fq = lane >> 4;

    const unsigned short* aBase = Abf + (size_t)(m0 + (t >> 2)) * LDA + (t & 3) * 8;
    const unsigned short* bBase = Wb  + (size_t)(n0 + (t >> 2)) * LDA + (t & 3) * 8;
    int ldsW = wave * 1024;

#define STAGE1(bufi, k0s)                                              \
    do {                                                               \
        char* AsB = (char*)As[bufi];  char* BsB = (char*)Bs[bufi];     \
        gload_lds16(aBase + (k0s),             AsB + ldsW);            \
        gload_lds16(aBase + 64 * LDA + (k0s),  AsB + 4096 + ldsW);     \
        gload_lds16(bBase + (k0s),             BsB + ldsW);            \
        gload_lds16(bBase + 64 * LDA + (k0s),  BsB + 4096 + ldsW);     \
    } while (0)

#define STEP1(c, nb, ti_)                                              \
    {                                                                  \
        asm volatile("s_waitcnt vmcnt(4)" ::: "memory");               \
        __builtin_amdgcn_s_barrier();                                  \
        if ((ti_) + 2 < NT) STAGE1(nb, ((ti_) + 2) * 32);              \
        COMPUTE_C(c);                                                  \
    }

    f32x4 acc[4][4] = {};

    STAGE1(0, 0);
    STAGE1(1, 32);
    for (int tg = 0; tg < 21; ++tg) {          // 63 steps, ring-static
        int ti = tg * 3;
        STEP1(0, 2, ti);
        STEP1(1, 0, ti + 1);
        STEP1(2, 1, ti + 2);
    }
    asm volatile("s_waitcnt vmcnt(0)" ::: "memory");   // tile 63
    __builtin_amdgcn_s_barrier();
    COMPUTE_C(0);
#undef STEP1
#undef STAGE1

    // epilogue: f = sigmoid(c + b1); Fout = f; H2 = bf16(f*h)
    int rowBase = m0 + wr * 64 + fq * 4;
    int colBase = n0 + wc * 64 + fr;
#pragma unroll
    for (int mi = 0; mi < 4; mi++) {
#pragma unroll
        for (int ni = 0; ni < 4; ni++) {
            int col = colBase + ni * 16;
            float b = bias[col];
#pragma unroll
            for (int j = 0; j < 4; j++) {
                int row = rowBase + mi * 16 + j;
                float c = acc[mi][ni][j] + b;
                float f = 1.0f / (1.0f + expf(-c));
                Fout[(size_t)row * N_DIM + col] = f;
                float hv = h[(size_t)row * N_DIM + col];
                H2[(size_t)row * LDH2 + col] = f2bf(f * hv);
            }
        }
    }
}

__global__ __launch_bounds__(256) void gemm2(
        const unsigned short* __restrict__ Abf,  // [M][LDA] bf16 (x half)
        const unsigned short* __restrict__ H2,   // [M][LDH2] bf16
        const unsigned short* __restrict__ Wb,   // [1024][LDA] bf16
        const float* __restrict__ bias,
        const float* __restrict__ h,
        float* Fout,                             // reads f, then overwritten
        float* Out2)
{
    __shared__ unsigned short As[3][4096];
    __shared__ unsigned short Bs[3][4096];

    int bid = blockIdx.x;
    int wg  = (bid & 7) * 128 + (bid >> 3);
    int tn = wg & 7, tm = wg >> 3;
    int m0 = tm * 128, n0 = tn * 128;

    int t = threadIdx.x, wave = t >> 6, lane = t & 63;
    int wr = wave >> 1, wc = wave & 1;
    int fr = lane & 15, fq = lane >> 4;

    const unsigned short* aBase1 = Abf + (size_t)(m0 + (t >> 2)) * LDA  + (t & 3) * 8;
    const unsigned short* aBase2 = H2  + (size_t)(m0 + (t >> 2)) * LDH2 + (t & 3) * 8;
    const unsigned short* bBase  = Wb  + (size_t)(n0 + (t >> 2)) * LDA  + (t & 3) * 8;
    int ldsW = wave * 1024;

#define STAGE2(bufi, k0s)                                                   \
    do {                                                                    \
        char* AsB = (char*)As[bufi];  char* BsB = (char*)Bs[bufi];          \
        if ((k0s) < 1024) {                                                 \
            gload_lds16(aBase1 + (k0s),             AsB + ldsW);            \
            gload_lds16(aBase1 + 64 * LDA + (k0s),  AsB + 4096 + ldsW);     \
        } else {                                                            \
            int kk = (k0s) - 1024;                                          \
            gload_lds16(aBase2 + kk,                AsB + ldsW);            \
            gload_lds16(aBase2 + 64 * LDH2 + kk,    AsB + 4096 + ldsW);     \
        }                                                                   \
        gload_lds16(bBase + (k0s),             BsB + ldsW);                 \
        gload_lds16(bBase + 64 * LDA + (k0s),  BsB + 4096 + ldsW);          \
    } while (0)

#define STEP2(c, nb, ti_)                                              \
    {                                                                  \
        asm volatile("s_waitcnt vmcnt(4)" ::: "memory");               \
        __builtin_amdgcn_s_barrier();                                  \
        if ((ti_) + 2 < NT) STAGE2(nb, ((ti_) + 2) * 32);              \
        COMPUTE_C(c);                                                  \
    }

    f32x4 acc[4][4] = {};

    STAGE2(0, 0);
    STAGE2(1, 32);
    for (int tg = 0; tg < 21; ++tg) {
        int ti = tg * 3;
        STEP2(0, 2, ti);
        STEP2(1, 0, ti + 1);
        STEP2(2, 1, ti + 2);
    }
    asm volatile("s_waitcnt vmcnt(0)" ::: "memory");
    __builtin_amdgcn_s_barrier();
    COMPUTE_C(0);
#undef STEP2
#undef STAGE2

    // epilogue: o = tanh(c + b2); out = h + f*(o - h); both tuple copies
    int rowBase = m0 + wr * 64 + fq * 4;
    int colBase = n0 + wc * 64 + fr;
#pragma unroll
    for (int mi = 0; mi < 4; mi++) {
#pragma unroll
        for (int ni = 0; ni < 4; ni++) {
            int col = colBase + ni * 16;
            float b = bias[col];
#pragma unroll
            for (int j = 0; j < 4; j++) {
                int row = rowBase + mi * 16 + j;
                size_t idx = (size_t)row * N_DIM + col;
                float c = acc[mi][ni][j] + b;
                float o = tanhf(c);
                float f = Fout[idx];
                float hv = h[idx];
                float out = fmaf(f, o - hv, hv);
                Fout[idx] = out;
                Out2[idx] = out;
            }
        }
    }
}

// ---------------- ablation instrument: gemm1 K-loop x2, NO epilogue ----------------
// Launched LAST; reads Abf/W1b (dead), sinks acc into W1b region (dead).
// Reads as its own row in the rocprof table: duration ~= 2 x (K-loop-only time).

__global__ __launch_bounds__(256) void abl_kloop(
        const unsigned short* __restrict__ Abf,
        const unsigned short* __restrict__ Wb,
        float* __restrict__ sink)
{
    __shared__ unsigned short As[3][4096];
    __shared__ unsigned short Bs[3][4096];

    int bid = blockIdx.x;
    int wg  = (bid & 7) * 128 + (bid >> 3);
    int tn = wg & 7, tm = wg >> 3;
    int m0 = tm * 128, n0 = tn * 128;

    int t = threadIdx.x, wave = t >> 6, lane = t & 63;
    int wr = wave >> 1, wc = wave & 1;
    int fr = lane & 15, fq = lane >> 4;

    const unsigned short* aBase = Abf + (size_t)(m0 + (t >> 2)) * LDA + (t & 3) * 8;
    const unsigned short* bBase = Wb  + (size_t)(n0 + (t >> 2)) * LDA + (t & 3) * 8;
    int ldsW = wave * 1024;

#define STAGEA(bufi, k0s)                                              \
    do {                                                               \
        char* AsB = (char*)As[bufi];  char* BsB = (char*)Bs[bufi];     \
        gload_lds16(aBase + (k0s),             AsB + ldsW);            \
        gload_lds16(aBase + 64 * LDA + (k0s),  AsB + 4096 + ldsW);     \
        gload_lds16(bBase + (k0s),             BsB + ldsW);            \
        gload_lds16(bBase + 64 * LDA + (k0s),  BsB + 4096 + ldsW);     \
    } while (0)

#define STEPA(c, nb, ti_)                                              \
    {                                                                  \
        asm volatile("s_waitcnt vmcnt(4)" ::: "memory");               \
        __builtin_amdgcn_s_barrier();                                  \
        if ((ti_) + 2 < NT) STAGEA(nb, ((ti_) + 2) * 32);              \
        COMPUTE_C(c);                                                  \
    }

    f32x4 acc[4][4] = {};

    for (int rep = 0; rep < 2; ++rep) {
        __syncthreads();                         // guard ring reuse across reps
        STAGEA(0, 0);
        STAGEA(1, 32);
        for (int tg = 0; tg < 21; ++tg) {
            int ti = tg * 3;
            STEPA(0, 2, ti);
            STEPA(1, 0, ti + 1);
            STEPA(2, 1, ti + 2);
        }
        asm volatile("s_waitcnt vmcnt(0)" ::: "memory");
        __builtin_amdgcn_s_barrier();
        COMPUTE_C(0);
    }
#undef STEPA
#undef STAGEA

    float s = 0.0f;
#pragma unroll
    for (int mi = 0; mi < 4; mi++)
#pragma unroll
        for (int ni = 0; ni < 4; ni++)
#pragma unroll
            for (int j = 0; j < 4; j++) s += acc[mi][ni][j];
    asm volatile("" :: "v"(s));                  // keep-alive (rule #17)
    sink[(size_t)blockIdx.x * 256 + threadIdx.x] = s;
}

// ---------------- launch ----------------

extern "C" void kernel_launch(void* const* d_in, const int* in_sizes, int n_in,
                              void* d_out, int out_size, void* d_ws, size_t ws_size,
                              hipStream_t stream) {
    const float* x  = (const float*)d_in[0];
    const float* h  = (const float*)d_in[1];
    const float* W1 = (const float*)d_in[2];
    const float* b1 = (const float*)d_in[3];
    const float* W2 = (const float*)d_in[4];
    const float* b2 = (const float*)d_in[5];
    float* out = (float*)d_out;
    float* out2 = out + (size_t)M_ROWS * N_DIM;

    // ws layout (109,608,960 B total; padded strides)
    unsigned short* Abf = (unsigned short*)d_ws;                             // 67,371,008
    unsigned short* H2  = (unsigned short*)((char*)d_ws + 67371008);         // 33,816,576
    unsigned short* W1b = (unsigned short*)((char*)d_ws + 101187584);        //  4,210,688
    unsigned short* W2b = (unsigned short*)((char*)d_ws + 105398272);        //  4,210,688

    pack_A<<<16384, 256, 0, stream>>>(x, h, Abf);
    pack_W<<<2048, 256, 0, stream>>>(W1, W2, W1b, W2b);
    gemm1<<<1024, 256, 0, stream>>>(Abf, W1b, b1, h, out, H2);
    gemm2<<<1024, 256, 0, stream>>>(Abf, H2, W2b, b2, h, out, out2);
    // instrument (reads dead Abf/W1b, writes dead W1b region) — runs last
    abl_kloop<<<1024, 256, 0, stream>>>(Abf, W1b, (float*)W1b);
}